// Round 1
// 1081.598 us; speedup vs baseline: 1.3114x; 1.3114x over previous
//
#include <hip/hip_runtime.h>

typedef __bf16 bf16;
typedef __attribute__((ext_vector_type(8))) __bf16 bf16x8;
typedef __attribute__((ext_vector_type(4))) __bf16 bf16x4;
typedef __attribute__((ext_vector_type(4))) float f32x4;
typedef __attribute__((ext_vector_type(4))) short s16x4;

#define SCALE 0.17677669529663687f   // 1/sqrt(32)

__device__ __forceinline__ f32x4 mfma16(bf16x8 a, bf16x8 b, f32x4 c) {
  return __builtin_amdgcn_mfma_f32_16x16x32_bf16(a, b, c, 0, 0, 0);
}

// K=16 bf16 MFMA. For K=16 the B-fragment layout (lane holds B[k=quad*4+j][n=l15])
// coincides with the MFMA C-layout of the v-projection output (vp[p=quad*4+r][d=l15]),
// so PV's B operand comes straight from registers -> no vpt LDS buffer, no K-pad.
__device__ __forceinline__ f32x4 mfma16k16(bf16x4 a, bf16x4 b, f32x4 c) {
#if __has_builtin(__builtin_amdgcn_mfma_f32_16x16x16bf16_1k)
  return __builtin_amdgcn_mfma_f32_16x16x16bf16_1k(
      __builtin_bit_cast(s16x4, a), __builtin_bit_cast(s16x4, b), c, 0, 0, 0);
#else
  asm("v_mfma_f32_16x16x16_bf16 %0, %1, %2, %0" : "+v"(c) : "v"(a), "v"(b));
  return c;
#endif
}

// ---------------------------------------------------------------------------
// prep: wt[c][k] = bf16(w_qkv[k][c])  (512x1536 -> 1536x512, row-major in k)
//       wpt[c][k] = bf16(w_proj[k][c]) (512x512)
// ---------------------------------------------------------------------------
__global__ void prep_weights(const float* __restrict__ w_qkv,
                             const float* __restrict__ w_proj,
                             bf16* __restrict__ wt, bf16* __restrict__ wpt) {
  __shared__ float tile[32][33];
  int b = blockIdx.x;
  const float* src; bf16* dst; int C, tk, tc;
  if (b < 768) {            // 16 k-tiles x 48 c-tiles
    src = w_qkv; dst = wt; C = 1536; tk = (b & 15) * 32; tc = (b >> 4) * 32;
  } else {                  // 16 x 16 tiles
    b -= 768; src = w_proj; dst = wpt; C = 512; tk = (b & 15) * 32; tc = (b >> 4) * 32;
  }
  int tx = threadIdx.x & 31, ty = threadIdx.x >> 5;
#pragma unroll
  for (int i = 0; i < 4; i++)
    tile[ty + i * 8][tx] = src[(size_t)(tk + ty + i * 8) * C + tc + tx];
  __syncthreads();
#pragma unroll
  for (int i = 0; i < 4; i++)
    dst[(size_t)(tc + ty + i * 8) * 512 + tk + tx] = (bf16)tile[tx][ty + i * 8];
}

// ---------------------------------------------------------------------------
// Fused window attention: one block (8 waves, 512 threads) per window.
// vs previous version: 8 waves (2 waves/SIMD when resident -> 2x occupancy),
// per-wave tiles halved, vpt LDS buffer eliminated via K=16 PV MFMA.
// ---------------------------------------------------------------------------
__launch_bounds__(512, 2)
__global__ void ewattn(const float* __restrict__ x,
                       const float* __restrict__ b_qkv,
                       const float* __restrict__ w_k,
                       const float* __restrict__ w_v,
                       const float* __restrict__ bias_table,
                       const float* __restrict__ b_proj,
                       const bf16* __restrict__ wt,
                       const bf16* __restrict__ wpt,
                       float* __restrict__ out) {
  // LDS: 66560 + 16640*2 + 2304*2 + 128 + 40960 + 10240 = 155776 B  (<160 KiB)
  __shared__ bf16 xs[64][520];      // phase A/B: bf16(x); phase C/D: reused as ao
  __shared__ bf16 xk[16][520];      // w_k @ x
  __shared__ bf16 xv[16][520];      // w_v @ x
  __shared__ bf16 wkl[16][72];
  __shared__ bf16 wvl[16][72];
  __shared__ float rs[32];          // rowsum(w_k)[16], rowsum(w_v)[16]
  __shared__ bf16 qs[8][64][40];    // per-wave: q staging, then attn-prob staging
  __shared__ bf16 kps[8][16][40];   // per-wave: k_proj [p][d]

  const int tid  = threadIdx.x;
  const int lane = tid & 63;
  const int wid  = tid >> 6;        // wave 0..7 -> heads 2w,2w+1; cols [64w, 64w+64)
  const int l15  = lane & 15;
  const int quad = lane >> 4;
  const int win  = blockIdx.x;
  const float* xw = x + (size_t)win * (64 * 512);

  // ---------------- Phase A: stage inputs ----------------
  for (int i = tid; i < 64 * 64; i += 512) {      // 64 rows x 8 groups of 8 floats
    int r = i >> 6, c8 = (i & 63) * 8;
    float4 v0 = *reinterpret_cast<const float4*>(xw + r * 512 + c8);
    float4 v1 = *reinterpret_cast<const float4*>(xw + r * 512 + c8 + 4);
    bf16x8 p;
    p[0] = (bf16)v0.x; p[1] = (bf16)v0.y; p[2] = (bf16)v0.z; p[3] = (bf16)v0.w;
    p[4] = (bf16)v1.x; p[5] = (bf16)v1.y; p[6] = (bf16)v1.z; p[7] = (bf16)v1.w;
    *reinterpret_cast<bf16x8*>(&xs[r][c8]) = p;   // row stride 1040 B = 65*16 -> aligned
  }
  for (int i = tid; i < 1024; i += 512) {
    int p = i >> 6, n = i & 63;
    wkl[p][n] = (bf16)w_k[i];
    wvl[p][n] = (bf16)w_v[i];
  }
  if (tid < 16) {
    float sk = 0.f, sv = 0.f;
#pragma unroll
    for (int n = 0; n < 64; n++) { sk += w_k[tid * 64 + n]; sv += w_v[tid * 64 + n]; }
    rs[tid] = sk; rs[16 + tid] = sv;
  }
  __syncthreads();

  // ---------------- Phase B ----------------
  // B2: xk = wk @ xs, xv = wv @ xs  (out [16][512]; this wave's 4 col-tiles)
  {
    f32x4 ak[4], av[4];
#pragma unroll
    for (int i = 0; i < 4; i++) { ak[i] = f32x4{0.f,0.f,0.f,0.f}; av[i] = f32x4{0.f,0.f,0.f,0.f}; }
#pragma unroll
    for (int kt = 0; kt < 2; kt++) {
      bf16x8 aK = *(const bf16x8*)&wkl[l15][kt * 32 + quad * 8];
      bf16x8 aV = *(const bf16x8*)&wvl[l15][kt * 32 + quad * 8];
      int n0 = kt * 32 + quad * 8;
#pragma unroll
      for (int nt = 0; nt < 4; nt++) {
        int c = wid * 64 + nt * 16 + l15;
        bf16x8 bb;                                 // B[k=n][c] = xs[n][c] (column walk)
#pragma unroll
        for (int j = 0; j < 8; j++) bb[j] = xs[n0 + j][c];
        ak[nt] = mfma16(aK, bb, ak[nt]);
        av[nt] = mfma16(aV, bb, av[nt]);
      }
    }
#pragma unroll
    for (int nt = 0; nt < 4; nt++) {
      int c = wid * 64 + nt * 16 + l15;
#pragma unroll
      for (int r = 0; r < 4; r++) {
        xk[quad * 4 + r][c] = (bf16)ak[nt][r];
        xv[quad * 4 + r][c] = (bf16)av[nt][r];
      }
    }
  }

  // B1: q (this wave's 64 cols) = xs @ wt[:512]; scale+bias folded; pack to bf16 regs
  bf16x4 qb[4][4];
  {
    f32x4 qacc[4][4];
#pragma unroll
    for (int nt = 0; nt < 4; nt++)
#pragma unroll
      for (int mt = 0; mt < 4; mt++) qacc[nt][mt] = f32x4{0.f,0.f,0.f,0.f};
    for (int kt = 0; kt < 16; kt++) {
      bf16x8 af[4];
#pragma unroll
      for (int mt = 0; mt < 4; mt++)
        af[mt] = *(const bf16x8*)&xs[mt * 16 + l15][kt * 32 + quad * 8];
#pragma unroll
      for (int nt = 0; nt < 4; nt++) {
        int c = wid * 64 + nt * 16 + l15;
        bf16x8 bb = *(const bf16x8*)&wt[(size_t)c * 512 + kt * 32 + quad * 8];
#pragma unroll
        for (int mt = 0; mt < 4; mt++)
          qacc[nt][mt] = mfma16(af[mt], bb, qacc[nt][mt]);
      }
    }
#pragma unroll
    for (int nt = 0; nt < 4; nt++) {
      float bq = b_qkv[wid * 64 + nt * 16 + l15];
#pragma unroll
      for (int mt = 0; mt < 4; mt++)
#pragma unroll
        for (int r = 0; r < 4; r++)
          qb[nt][mt][r] = (bf16)((qacc[nt][mt][r] + bq) * SCALE);
    }
  }
  __syncthreads();   // xk/xv visible to all; xs reads done -> reusable as ao

  // ---------------- Phase C: 2 heads per wave ----------------
  float rsk[4], rsv[4];
#pragma unroll
  for (int j = 0; j < 4; j++) { rsk[j] = rs[quad * 4 + j]; rsv[j] = rs[16 + quad * 4 + j]; }

  for (int hi = 0; hi < 2; hi++) {
    const int h = wid * 2 + hi;

    // k_proj/v_proj [16][32] = xk/xv @ wt cols, + rowsum-folded bias
    f32x4 kp[2], vp[2];
    kp[0] = kp[1] = vp[0] = vp[1] = f32x4{0.f,0.f,0.f,0.f};
    for (int kt = 0; kt < 16; kt++) {
      bf16x8 aK = *(const bf16x8*)&xk[l15][kt * 32 + quad * 8];
      bf16x8 aV = *(const bf16x8*)&xv[l15][kt * 32 + quad * 8];
#pragma unroll
      for (int nt = 0; nt < 2; nt++) {
        int ck = 512 + h * 32 + nt * 16 + l15;
        int cv = 1024 + h * 32 + nt * 16 + l15;
        bf16x8 bk = *(const bf16x8*)&wt[(size_t)ck * 512 + kt * 32 + quad * 8];
        bf16x8 bv = *(const bf16x8*)&wt[(size_t)cv * 512 + kt * 32 + quad * 8];
        kp[nt] = mfma16(aK, bk, kp[nt]);
        vp[nt] = mfma16(aV, bv, vp[nt]);
      }
    }
    // k_proj -> LDS staging [p][d] (needed: attn B-frag wants full row per lane)
#pragma unroll
    for (int nt = 0; nt < 2; nt++) {
      float bk = b_qkv[512 + h * 32 + nt * 16 + l15];
#pragma unroll
      for (int r = 0; r < 4; r++)
        kps[wid][quad * 4 + r][nt * 16 + l15] = (bf16)(kp[nt][r] + rsk[r] * bk);
    }
    // v_proj stays in registers: C-layout == K=16 B-frag layout
    bf16x4 bvf[2];
#pragma unroll
    for (int nd = 0; nd < 2; nd++) {
      float bv = b_qkv[1024 + h * 32 + nd * 16 + l15];
#pragma unroll
      for (int j = 0; j < 4; j++)
        bvf[nd][j] = (bf16)(vp[nd][j] + rsv[j] * bv);
    }

    // stage q for this head (local d = 0..31)
#pragma unroll
    for (int nn = 0; nn < 2; nn++)
#pragma unroll
      for (int mt = 0; mt < 4; mt++)
#pragma unroll
        for (int r = 0; r < 4; r++)
          qs[wid][mt * 16 + quad * 4 + r][nn * 16 + l15] = qb[hi * 2 + nn][mt][r];

    // attn = q @ k_proj^T : [64][16], K=32
    f32x4 at[4];
    {
      bf16x8 bk2 = *(const bf16x8*)&kps[wid][l15][quad * 8];
#pragma unroll
      for (int mt = 0; mt < 4; mt++) {
        bf16x8 aq = *(const bf16x8*)&qs[wid][mt * 16 + l15][quad * 8];
        at[mt] = mfma16(aq, bk2, f32x4{0.f,0.f,0.f,0.f});
      }
    }

    // rel-pos bias + softmax over p (row n lives in the 16 lanes of this quad)
    float pr[4][4];
#pragma unroll
    for (int mt = 0; mt < 4; mt++) {
#pragma unroll
      for (int r = 0; r < 4; r++) {
        int n = mt * 16 + quad * 4 + r;
        int rel = ((n >> 3) - (l15 >> 3) + 7) * 15 + ((n & 7) - (l15 & 7) + 7);
        float e = __expf(at[mt][r] + bias_table[rel * 16 + h]);
        float s = e;
        s += __shfl_xor(s, 1); s += __shfl_xor(s, 2);
        s += __shfl_xor(s, 4); s += __shfl_xor(s, 8);
        pr[mt][r] = e * __builtin_amdgcn_rcpf(s);
      }
    }

    // probs -> qs cols 0..15
#pragma unroll
    for (int mt = 0; mt < 4; mt++)
#pragma unroll
      for (int r = 0; r < 4; r++)
        qs[wid][mt * 16 + quad * 4 + r][l15] = (bf16)pr[mt][r];

    // out_head [64][32] = probs @ v_proj  (exact K=16, B operand from registers)
    f32x4 ov[2][4];
#pragma unroll
    for (int mt = 0; mt < 4; mt++) {
      bf16x4 ap = *(const bf16x4*)&qs[wid][mt * 16 + l15][quad * 4];
#pragma unroll
      for (int nd = 0; nd < 2; nd++)
        ov[nd][mt] = mfma16k16(ap, bvf[nd], f32x4{0.f,0.f,0.f,0.f});
    }
    // write head output into ao (= xs buffer), cols h*32..h*32+31
#pragma unroll
    for (int nd = 0; nd < 2; nd++)
#pragma unroll
      for (int mt = 0; mt < 4; mt++)
#pragma unroll
        for (int r = 0; r < 4; r++)
          xs[mt * 16 + quad * 4 + r][h * 32 + nd * 16 + l15] = (bf16)ov[nd][mt][r];
  }
  __syncthreads();   // all heads' ao written

  // ---------------- Phase D: out = ao @ w_proj + b_proj ----------------
  {
    f32x4 oacc[4][4];
#pragma unroll
    for (int nt = 0; nt < 4; nt++)
#pragma unroll
      for (int mt = 0; mt < 4; mt++) oacc[nt][mt] = f32x4{0.f,0.f,0.f,0.f};
    for (int kt = 0; kt < 16; kt++) {
      bf16x8 af[4];
#pragma unroll
      for (int mt = 0; mt < 4; mt++)
        af[mt] = *(const bf16x8*)&xs[mt * 16 + l15][kt * 32 + quad * 8];
#pragma unroll
      for (int nt = 0; nt < 4; nt++) {
        int c = wid * 64 + nt * 16 + l15;
        bf16x8 bb = *(const bf16x8*)&wpt[(size_t)c * 512 + kt * 32 + quad * 8];
#pragma unroll
        for (int mt = 0; mt < 4; mt++)
          oacc[nt][mt] = mfma16(af[mt], bb, oacc[nt][mt]);
      }
    }
    float* ow = out + (size_t)win * (64 * 512);
#pragma unroll
    for (int nt = 0; nt < 4; nt++) {
      int c = wid * 64 + nt * 16 + l15;
      float bp = b_proj[c];
#pragma unroll
      for (int mt = 0; mt < 4; mt++)
#pragma unroll
        for (int r = 0; r < 4; r++)
          ow[(size_t)(mt * 16 + quad * 4 + r) * 512 + c] = oacc[nt][mt][r] + bp;
    }
  }
}

extern "C" void kernel_launch(void* const* d_in, const int* in_sizes, int n_in,
                              void* d_out, int out_size, void* d_ws, size_t ws_size,
                              hipStream_t stream) {
  const float* x          = (const float*)d_in[0];
  const float* w_qkv      = (const float*)d_in[1];
  const float* b_qkv      = (const float*)d_in[2];
  const float* w_proj     = (const float*)d_in[3];
  const float* b_proj     = (const float*)d_in[4];
  const float* w_k        = (const float*)d_in[5];
  const float* w_v        = (const float*)d_in[6];
  const float* bias_table = (const float*)d_in[7];
  (void)in_sizes; (void)n_in; (void)out_size; (void)ws_size;

  bf16* wt  = (bf16*)d_ws;            // [1536][512]
  bf16* wpt = wt + 1536 * 512;        // [512][512]

  prep_weights<<<1024, 256, 0, stream>>>(w_qkv, w_proj, wt, wpt);
  ewattn<<<2048, 512, 0, stream>>>(x, b_qkv, w_k, w_v, bias_table, b_proj,
                                   wt, wpt, (float*)d_out);
}

// Round 2
// 933.474 us; speedup vs baseline: 1.5195x; 1.1587x over previous
//
#include <hip/hip_runtime.h>

typedef __bf16 bf16;
typedef __attribute__((ext_vector_type(8))) __bf16 bf16x8;
typedef __attribute__((ext_vector_type(4))) __bf16 bf16x4;
typedef __attribute__((ext_vector_type(4))) float f32x4;
typedef __attribute__((ext_vector_type(4))) short s16x4;

#define SCALE 0.17677669529663687f   // 1/sqrt(32)

__device__ __forceinline__ f32x4 mfma16(bf16x8 a, bf16x8 b, f32x4 c) {
  return __builtin_amdgcn_mfma_f32_16x16x32_bf16(a, b, c, 0, 0, 0);
}

// K=16 bf16 MFMA. Layout (verified by the passing round-1 kernel):
//   A: lane holds A[m=l15][k=quad*4+j]   B: lane holds B[k=quad*4+j][n=l15]
//   C: lane holds C[row=quad*4+r][col=l15]
__device__ __forceinline__ f32x4 mfma16k16(bf16x4 a, bf16x4 b, f32x4 c) {
#if __has_builtin(__builtin_amdgcn_mfma_f32_16x16x16bf16_1k)
  return __builtin_amdgcn_mfma_f32_16x16x16bf16_1k(
      __builtin_bit_cast(s16x4, a), __builtin_bit_cast(s16x4, b), c, 0, 0, 0);
#else
  asm("v_mfma_f32_16x16x16_bf16 %0, %1, %2, %0" : "+v"(c) : "v"(a), "v"(b));
  return c;
#endif
}

// ---------------------------------------------------------------------------
// prep: wt[c][k] = bf16(w_qkv[k][c])  (512x1536 -> 1536x512, row-major in k)
//       wpt[c][k] = bf16(w_proj[k][c]) (512x512)
// ---------------------------------------------------------------------------
__global__ void prep_weights(const float* __restrict__ w_qkv,
                             const float* __restrict__ w_proj,
                             bf16* __restrict__ wt, bf16* __restrict__ wpt) {
  __shared__ float tile[32][33];
  int b = blockIdx.x;
  const float* src; bf16* dst; int C, tk, tc;
  if (b < 768) {            // 16 k-tiles x 48 c-tiles
    src = w_qkv; dst = wt; C = 1536; tk = (b & 15) * 32; tc = (b >> 4) * 32;
  } else {                  // 16 x 16 tiles
    b -= 768; src = w_proj; dst = wpt; C = 512; tk = (b & 15) * 32; tc = (b >> 4) * 32;
  }
  int tx = threadIdx.x & 31, ty = threadIdx.x >> 5;
#pragma unroll
  for (int i = 0; i < 4; i++)
    tile[ty + i * 8][tx] = src[(size_t)(tk + ty + i * 8) * C + tc + tx];
  __syncthreads();
#pragma unroll
  for (int i = 0; i < 4; i++)
    dst[(size_t)(tc + ty + i * 8) * 512 + tk + tx] = (bf16)tile[tx][ty + i * 8];
}

// ---------------------------------------------------------------------------
// Fused window attention: one block (16 waves, 1024 threads) per window.
// Wave w = head w.  4 waves/SIMD when resident (2x round-1 occupancy).
// Transposed-intermediate layout chain (all register-resident phase C):
//   B1 computes qT: C-layout lane=token, regs=channel ct*16+quad*4+r
//      -> IS the K=16 B-frag B[k=d][n=token] for QK^T (ct = h*2+ks)
//   kp computed as kpT (swap mfma operands): C-layout lane=p, regs=d
//      -> IS the K=16 A-frag A[m=p][k=d] for QK^T
//   QK^T out: lane=token, p=(quad,reg) -> softmax: 4-reg sum + shfl_xor 16/32
//      -> probs ARE the K=16 A-frag A[m=token][k=p] for PV
//   vp C-layout (lane=d, regs=p) IS the K=16 B-frag for PV (round-1 trick)
// ---------------------------------------------------------------------------
__launch_bounds__(1024, 4)
__global__ void ewattn(const float* __restrict__ x,
                       const float* __restrict__ b_qkv,
                       const float* __restrict__ w_k,
                       const float* __restrict__ w_v,
                       const float* __restrict__ bias_table,
                       const float* __restrict__ b_proj,
                       const bf16* __restrict__ wt,
                       const bf16* __restrict__ wpt,
                       float* __restrict__ out) {
  // LDS: 66560 + 16640*2 + 2304*2 + 128 = 104576 B
  __shared__ bf16 xs[64][520];      // phase A/B: bf16(x); phase C/D: reused as ao
  __shared__ bf16 xk[16][520];      // w_k @ x
  __shared__ bf16 xv[16][520];      // w_v @ x
  __shared__ bf16 wkl[16][72];
  __shared__ bf16 wvl[16][72];
  __shared__ float rs[32];          // rowsum(w_k)[16], rowsum(w_v)[16]

  const int tid  = threadIdx.x;
  const int lane = tid & 63;
  const int wid  = tid >> 6;        // wave 0..15 == head
  const int l15  = lane & 15;
  const int quad = lane >> 4;
  const int win  = blockIdx.x;
  const float* xw = x + (size_t)win * (64 * 512);

  // ---------------- Phase A: stage inputs ----------------
  for (int i = tid; i < 64 * 64; i += 1024) {     // 64 rows x 8 groups of 8 floats
    int r = i >> 6, c8 = (i & 63) * 8;
    float4 v0 = *reinterpret_cast<const float4*>(xw + r * 512 + c8);
    float4 v1 = *reinterpret_cast<const float4*>(xw + r * 512 + c8 + 4);
    bf16x8 p;
    p[0] = (bf16)v0.x; p[1] = (bf16)v0.y; p[2] = (bf16)v0.z; p[3] = (bf16)v0.w;
    p[4] = (bf16)v1.x; p[5] = (bf16)v1.y; p[6] = (bf16)v1.z; p[7] = (bf16)v1.w;
    *reinterpret_cast<bf16x8*>(&xs[r][c8]) = p;   // row stride 1040 B -> 16B aligned
  }
  {                                               // 1024 threads, 1024 elements
    int p = tid >> 6, n = tid & 63;
    wkl[p][n] = (bf16)w_k[tid];
    wvl[p][n] = (bf16)w_v[tid];
  }
  if (tid < 16) {
    float sk = 0.f, sv = 0.f;
#pragma unroll
    for (int n = 0; n < 64; n++) { sk += w_k[tid * 64 + n]; sv += w_v[tid * 64 + n]; }
    rs[tid] = sk; rs[16 + tid] = sv;
  }
  __syncthreads();

  // ---------------- Phase B2: xk = wk @ xs, xv = wv @ xs (2 col-tiles/wave) --
  {
    f32x4 ak[2], av[2];
#pragma unroll
    for (int i = 0; i < 2; i++) { ak[i] = f32x4{0.f,0.f,0.f,0.f}; av[i] = f32x4{0.f,0.f,0.f,0.f}; }
#pragma unroll
    for (int kt = 0; kt < 2; kt++) {
      bf16x8 aK = *(const bf16x8*)&wkl[l15][kt * 32 + quad * 8];
      bf16x8 aV = *(const bf16x8*)&wvl[l15][kt * 32 + quad * 8];
      int n0 = kt * 32 + quad * 8;
#pragma unroll
      for (int nt = 0; nt < 2; nt++) {
        int c = wid * 32 + nt * 16 + l15;
        bf16x8 bb;                                 // B[k=n][c] = xs[n][c] (column walk)
#pragma unroll
        for (int j = 0; j < 8; j++) bb[j] = xs[n0 + j][c];
        ak[nt] = mfma16(aK, bb, ak[nt]);
        av[nt] = mfma16(aV, bb, av[nt]);
      }
    }
#pragma unroll
    for (int nt = 0; nt < 2; nt++) {
      int c = wid * 32 + nt * 16 + l15;
#pragma unroll
      for (int r = 0; r < 4; r++) {
        xk[quad * 4 + r][c] = (bf16)ak[nt][r];
        xv[quad * 4 + r][c] = (bf16)av[nt][r];
      }
    }
  }

  // ---------------- Phase B1: qT = Wq^T @ x^T (this head's 32 channels) -----
  // A = wt rows (m = channel), B = xs rows (n = token). Output C-layout:
  // lane l15 = token, reg (ct,r): q[token][wid*32 + ct*16 + quad*4 + r]
  bf16x4 qb[2][4];                  // [ct = ks][tt = token tile]
  {
    f32x4 qacc[2][4];
#pragma unroll
    for (int ct = 0; ct < 2; ct++)
#pragma unroll
      for (int tt = 0; tt < 4; tt++) qacc[ct][tt] = f32x4{0.f,0.f,0.f,0.f};
    for (int kt = 0; kt < 16; kt++) {
      bf16x8 aw[2];
#pragma unroll
      for (int ct = 0; ct < 2; ct++)
        aw[ct] = *(const bf16x8*)&wt[(size_t)(wid * 32 + ct * 16 + l15) * 512 + kt * 32 + quad * 8];
      bf16x8 bx[4];
#pragma unroll
      for (int tt = 0; tt < 4; tt++)
        bx[tt] = *(const bf16x8*)&xs[tt * 16 + l15][kt * 32 + quad * 8];
#pragma unroll
      for (int ct = 0; ct < 2; ct++)
#pragma unroll
        for (int tt = 0; tt < 4; tt++)
          qacc[ct][tt] = mfma16(aw[ct], bx[tt], qacc[ct][tt]);
    }
#pragma unroll
    for (int ct = 0; ct < 2; ct++)
#pragma unroll
      for (int tt = 0; tt < 4; tt++)
#pragma unroll
        for (int r = 0; r < 4; r++)
          qb[ct][tt][r] = (bf16)((qacc[ct][tt][r] +
                                  b_qkv[wid * 32 + ct * 16 + quad * 4 + r]) * SCALE);
  }
  __syncthreads();   // xk/xv visible; all xs reads done -> reusable as ao

  // ---------------- Phase C: one head per wave, all in registers ------------
  const int h = wid;
  f32x4 kpa[2], vpa[2];             // kpT: lane=p, regs=d ; vp: lane=d, regs=p
  kpa[0] = kpa[1] = vpa[0] = vpa[1] = f32x4{0.f,0.f,0.f,0.f};
  for (int kt = 0; kt < 16; kt++) {
    bf16x8 xkf = *(const bf16x8*)&xk[l15][kt * 32 + quad * 8];
    bf16x8 xvf = *(const bf16x8*)&xv[l15][kt * 32 + quad * 8];
#pragma unroll
    for (int nt = 0; nt < 2; nt++) {
      bf16x8 wkf = *(const bf16x8*)&wt[(size_t)(512  + h * 32 + nt * 16 + l15) * 512 + kt * 32 + quad * 8];
      bf16x8 wvf = *(const bf16x8*)&wt[(size_t)(1024 + h * 32 + nt * 16 + l15) * 512 + kt * 32 + quad * 8];
      kpa[nt] = mfma16(wkf, xkf, kpa[nt]);   // kpT = Wk^T @ xk^T
      vpa[nt] = mfma16(xvf, wvf, vpa[nt]);   // vp  = xv @ Wv
    }
  }
  // fold rowsum-bias; pack to MFMA fragments
  float rskl = rs[l15];
  float rsvr[4];
#pragma unroll
  for (int r = 0; r < 4; r++) rsvr[r] = rs[16 + quad * 4 + r];
  bf16x4 kpf[2], bvf[2];
#pragma unroll
  for (int nt = 0; nt < 2; nt++) {
    float bvb = b_qkv[1024 + h * 32 + nt * 16 + l15];
#pragma unroll
    for (int r = 0; r < 4; r++) {
      kpf[nt][r] = (bf16)(kpa[nt][r] + rskl * b_qkv[512 + h * 32 + nt * 16 + quad * 4 + r]);
      bvf[nt][r] = (bf16)(vpa[nt][r] + rsvr[r] * bvb);
    }
  }

#pragma unroll
  for (int tt = 0; tt < 4; tt++) {
    // QK^T (K=32 as 2x K=16): out lane=token (=tt*16+l15), p = quad*4+r
    f32x4 att = mfma16k16(kpf[0], qb[0][tt], f32x4{0.f,0.f,0.f,0.f});
    att = mfma16k16(kpf[1], qb[1][tt], att);
    // rel-pos bias + softmax over p (4 regs + quad dimension)
    int n = tt * 16 + l15;
    float e[4], s = 0.f;
#pragma unroll
    for (int r = 0; r < 4; r++) {
      int p = quad * 4 + r;
      int rel = ((n >> 3) - (p >> 3) + 7) * 15 + ((n & 7) - (p & 7) + 7);
      e[r] = __expf(att[r] + bias_table[rel * 16 + h]);
      s += e[r];
    }
    s += __shfl_xor(s, 16); s += __shfl_xor(s, 32);
    float rc = __builtin_amdgcn_rcpf(s);
    bf16x4 ap;
#pragma unroll
    for (int r = 0; r < 4; r++) ap[r] = (bf16)(e[r] * rc);
    // PV (K=16 exact): A = probs (regs), B = vp (regs)
#pragma unroll
    for (int nd = 0; nd < 2; nd++) {
      f32x4 ov = mfma16k16(ap, bvf[nd], f32x4{0.f,0.f,0.f,0.f});
#pragma unroll
      for (int r = 0; r < 4; r++)
        xs[tt * 16 + quad * 4 + r][h * 32 + nd * 16 + l15] = (bf16)ov[r];
    }
  }
  __syncthreads();   // all heads' ao written

  // ---------------- Phase D: out = ao @ w_proj + b_proj (2 col-tiles/wave) --
  {
    f32x4 oacc[4][2];
#pragma unroll
    for (int mt = 0; mt < 4; mt++)
#pragma unroll
      for (int nt = 0; nt < 2; nt++) oacc[mt][nt] = f32x4{0.f,0.f,0.f,0.f};
    for (int kt = 0; kt < 16; kt++) {
      bf16x8 af[4];
#pragma unroll
      for (int mt = 0; mt < 4; mt++)
        af[mt] = *(const bf16x8*)&xs[mt * 16 + l15][kt * 32 + quad * 8];
      bf16x8 bw[2];
#pragma unroll
      for (int nt = 0; nt < 2; nt++)
        bw[nt] = *(const bf16x8*)&wpt[(size_t)(wid * 32 + nt * 16 + l15) * 512 + kt * 32 + quad * 8];
#pragma unroll
      for (int mt = 0; mt < 4; mt++)
#pragma unroll
        for (int nt = 0; nt < 2; nt++)
          oacc[mt][nt] = mfma16(af[mt], bw[nt], oacc[mt][nt]);
    }
    float* ow = out + (size_t)win * (64 * 512);
#pragma unroll
    for (int nt = 0; nt < 2; nt++) {
      int c = wid * 32 + nt * 16 + l15;
      float bp = b_proj[c];
#pragma unroll
      for (int mt = 0; mt < 4; mt++)
#pragma unroll
        for (int r = 0; r < 4; r++)
          ow[(size_t)(mt * 16 + quad * 4 + r) * 512 + c] = oacc[mt][nt][r] + bp;
    }
  }
}

extern "C" void kernel_launch(void* const* d_in, const int* in_sizes, int n_in,
                              void* d_out, int out_size, void* d_ws, size_t ws_size,
                              hipStream_t stream) {
  const float* x          = (const float*)d_in[0];
  const float* w_qkv      = (const float*)d_in[1];
  const float* b_qkv      = (const float*)d_in[2];
  const float* w_proj     = (const float*)d_in[3];
  const float* b_proj     = (const float*)d_in[4];
  const float* w_k        = (const float*)d_in[5];
  const float* w_v        = (const float*)d_in[6];
  const float* bias_table = (const float*)d_in[7];
  (void)in_sizes; (void)n_in; (void)out_size; (void)ws_size;

  bf16* wt  = (bf16*)d_ws;            // [1536][512]
  bf16* wpt = wt + 1536 * 512;        // [512][512]

  prep_weights<<<1024, 256, 0, stream>>>(w_qkv, w_proj, wt, wpt);
  ewattn<<<2048, 1024, 0, stream>>>(x, b_qkv, w_k, w_v, bias_table, b_proj,
                                    wt, wpt, (float*)d_out);
}